// Round 1
// baseline (143.449 us; speedup 1.0000x reference)
//
#include <hip/hip_runtime.h>
#include <cstdint>
#include <cstddef>

typedef __bf16 bf16;
typedef __bf16 bf16x8 __attribute__((ext_vector_type(8)));
typedef float  f32x4  __attribute__((ext_vector_type(4)));

#define MFMA16(a,b,c) __builtin_amdgcn_mfma_f32_16x16x32_bf16((a),(b),(c),0,0,0)

__device__ __forceinline__ void gload_lds16(const bf16* g, bf16* l) {
  __builtin_amdgcn_global_load_lds((__attribute__((address_space(1))) void*)(g),
                                   (__attribute__((address_space(3))) void*)(l),
                                   16, 0, 0);
}

// ---------------- cast fp32 -> bf16 (vectorized) ----------------
__global__ void cast_bf16_k(const float* __restrict__ src, bf16* __restrict__ dst, int n) {
  int i = (blockIdx.x * blockDim.x + threadIdx.x) * 4;
  if (i >= n) return;
  float4 v = *(const float4*)(src + i);
  dst[i + 0] = (bf16)v.x;
  dst[i + 1] = (bf16)v.y;
  dst[i + 2] = (bf16)v.z;
  dst[i + 3] = (bf16)v.w;
}

// ---------------- transpose + cast: dst[c,r] = src[r,c] ----------------
__global__ void transpose_cast_k(const float* __restrict__ src, bf16* __restrict__ dst,
                                 int R, int C) {
  __shared__ float t[32][33];
  const int c0 = blockIdx.x * 32, r0 = blockIdx.y * 32;
  const int x = threadIdx.x, y = threadIdx.y;
  #pragma unroll
  for (int j = 0; j < 32; j += 8) t[y + j][x] = src[(size_t)(r0 + y + j) * C + c0 + x];
  __syncthreads();
  #pragma unroll
  for (int j = 0; j < 32; j += 8)
    dst[(size_t)(c0 + y + j) * R + r0 + x] = (bf16)t[x][y + j];
}

// ---------------- 128x128-tile bf16 GEMM, C = A @ Bt^T ----------------
// A: [M,1024] row-major bf16; Bt: [Ncol,1024] row-major bf16 (i.e. B^T).
// mode 0: out bf16 head-split [b,h,i,d]; mode 1: out bf16 [b,h,d,i] (V^T);
// mode 2: out fp32 [row,col] + bias. mode_sel=-1 -> derive from blockIdx.z (z==2 -> 1).
__global__ __launch_bounds__(256) void gemm128(
    const bf16* __restrict__ A, const bf16* __restrict__ Bt0,
    bf16* __restrict__ O0, float* __restrict__ Of,
    const float* __restrict__ bias, const int mode_sel) {
  constexpr int K = 1024;
  const int z = blockIdx.z;
  const bf16* Bt = Bt0 + (size_t)z * (1024 * 1024);
  bf16* Ob = O0 + (size_t)z * (2048 * 1024);
  const int mode = (mode_sel < 0) ? ((z == 2) ? 1 : 0) : mode_sel;

  const int row0 = blockIdx.x * 128;
  const int col0 = blockIdx.y * 128;

  __shared__ bf16 As[128 * 32];
  __shared__ bf16 Bs[128 * 32];

  const int tid = threadIdx.x;
  const int lane = tid & 63;
  const int wid = tid >> 6;
  const int lr = lane & 15;
  const int lk = (lane >> 4) * 8;
  const int wr = (wid >> 1) * 64;
  const int wc = (wid & 1) * 64;
  const int sr = lane >> 2;         // staging row within 16-row chunk
  const int sc = (lane & 3) * 8;    // staging col offset

  f32x4 acc[4][4];
  #pragma unroll
  for (int a = 0; a < 4; ++a)
    #pragma unroll
    for (int b = 0; b < 4; ++b) acc[a][b] = (f32x4){0.f, 0.f, 0.f, 0.f};

  for (int k0 = 0; k0 < K; k0 += 32) {
    __syncthreads();
    #pragma unroll
    for (int q = 0; q < 2; ++q) {
      const int chunk = wid * 2 + q;
      const int r = chunk * 16 + sr;
      gload_lds16(A  + (size_t)(row0 + r) * K + k0 + sc, &As[chunk * 512]);
      gload_lds16(Bt + (size_t)(col0 + r) * K + k0 + sc, &Bs[chunk * 512]);
    }
    __syncthreads();
    bf16x8 af[4], bfv[4];
    #pragma unroll
    for (int mi = 0; mi < 4; ++mi) af[mi] = *(const bf16x8*)&As[(wr + mi * 16 + lr) * 32 + lk];
    #pragma unroll
    for (int ni = 0; ni < 4; ++ni) bfv[ni] = *(const bf16x8*)&Bs[(wc + ni * 16 + lr) * 32 + lk];
    #pragma unroll
    for (int mi = 0; mi < 4; ++mi)
      #pragma unroll
      for (int ni = 0; ni < 4; ++ni)
        acc[mi][ni] = MFMA16(af[mi], bfv[ni], acc[mi][ni]);
  }

  #pragma unroll
  for (int mi = 0; mi < 4; ++mi) {
    #pragma unroll
    for (int ni = 0; ni < 4; ++ni) {
      #pragma unroll
      for (int r = 0; r < 4; ++r) {
        const int row = row0 + wr + mi * 16 + (lane >> 4) * 4 + r;
        const int col = col0 + wc + ni * 16 + lr;
        const float v = acc[mi][ni][r];
        if (mode == 2) {
          Of[(size_t)row * 1024 + col] = v + bias[col];
        } else {
          const int b = row >> 10, i = row & 1023;
          const int h = col >> 6, d = col & 63;
          if (mode == 0)
            Ob[(((size_t)(b * 16 + h)) * 1024 + i) * 64 + d] = (bf16)v;
          else
            Ob[(((size_t)(b * 16 + h)) * 64 + d) * 1024 + i] = (bf16)v;
        }
      }
    }
  }
}

// ---------------- causal flash attention with relative-position band ----------------
// Qh,Kh: [B*H, N, 64] bf16; Vt: [B*H, 64, N] bf16; Eb: [2047,64] bf16 (rows 0..2046).
// AO: [B*N, 1024] bf16 (heads concatenated).
__global__ __launch_bounds__(256) void attn_kernel(
    const bf16* __restrict__ Qh, const bf16* __restrict__ Kh,
    const bf16* __restrict__ Vt, const bf16* __restrict__ Eb,
    bf16* __restrict__ AO) {
  constexpr int N = 1024, DH = 64;
  const int qb = (int)(gridDim.x - 1 - blockIdx.x);  // heavy blocks first
  const int bh = blockIdx.y;
  const int i0 = qb * 64;

  const bf16* Qp = Qh + (size_t)bh * N * DH;
  const bf16* Kp = Kh + (size_t)bh * N * DH;
  const bf16* Vp = Vt + (size_t)bh * DH * N;

  __shared__ bf16 Qs[64 * 64];
  __shared__ bf16 Ks[64 * 64];
  __shared__ bf16 Vs[64 * 64];
  __shared__ bf16 Es[128 * 64];
  __shared__ float QEw[4][16 * 128];
  __shared__ bf16 Ps[4][16 * 64];

  const int tid = threadIdx.x;
  const int lane = tid & 63;
  const int wid = tid >> 6;
  const int lr = lane & 15;
  const int g = lane >> 4;
  const int lk = g * 8;

  #pragma unroll
  for (int c = 0; c < 2; ++c) {
    const int idx = c * 256 + tid;
    *(bf16x8*)&Qs[idx * 8] = *(const bf16x8*)&Qp[i0 * DH + idx * 8];
  }
  __syncthreads();

  bf16x8 qf[2];
  qf[0] = *(const bf16x8*)&Qs[(wid * 16 + lr) * 64 + lk];
  qf[1] = *(const bf16x8*)&Qs[(wid * 16 + lr) * 64 + 32 + lk];

  float m_r[4], l_r[4];
  f32x4 oacc[4];
  #pragma unroll
  for (int r = 0; r < 4; ++r) {
    m_r[r] = -__builtin_inff();
    l_r[r] = 0.f;
    oacc[r] = (f32x4){0.f, 0.f, 0.f, 0.f};
  }

  const int iw0 = i0 + wid * 16;
  const int nkb = qb + 1;
  const int sib = 3 - wid;  // first needed 16-wide E-window fragment for this wave
  float* qw = &QEw[wid][0];
  bf16* pp = &Ps[wid][0];

  for (int kb = 0; kb < nkb; ++kb) {
    const int j0 = kb * 64;
    __syncthreads();
    // stage K block [64,64]
    #pragma unroll
    for (int c = 0; c < 2; ++c) {
      const int idx = c * 256 + tid;
      *(bf16x8*)&Ks[idx * 8] = *(const bf16x8*)&Kp[j0 * DH + idx * 8];
    }
    // stage E window [128,64], rows rbase..rbase+127 (always within [0,2047))
    {
      const int rbase = N - 64 + j0 - i0;
      #pragma unroll
      for (int c = 0; c < 4; ++c) {
        const int idx = c * 256 + tid;
        *(bf16x8*)&Es[idx * 8] = *(const bf16x8*)&Eb[rbase * DH + idx * 8];
      }
    }
    // stage V^T block [64 d][64 keys]
    #pragma unroll
    for (int c = 0; c < 2; ++c) {
      const int idx = c * 256 + tid;
      const int d = idx >> 3, off = (idx & 7) * 8;
      *(bf16x8*)&Vs[d * 64 + off] = *(const bf16x8*)&Vp[(size_t)d * N + j0 + off];
    }
    __syncthreads();

    if (j0 <= iw0 + 15) {  // wave-uniform: any unmasked element for this wave's rows
      // --- Q @ E-window^T : only the 5 needed 16-col fragments ---
      f32x4 ea[5];
      #pragma unroll
      for (int s5 = 0; s5 < 5; ++s5) ea[s5] = (f32x4){0.f, 0.f, 0.f, 0.f};
      #pragma unroll
      for (int s5 = 0; s5 < 5; ++s5) {
        const int si = sib + s5;
        #pragma unroll
        for (int kk = 0; kk < 2; ++kk) {
          bf16x8 ef = *(const bf16x8*)&Es[(si * 16 + lr) * 64 + kk * 32 + lk];
          ea[s5] = MFMA16(qf[kk], ef, ea[s5]);
        }
      }
      #pragma unroll
      for (int s5 = 0; s5 < 5; ++s5) {
        const int si = sib + s5;
        #pragma unroll
        for (int r = 0; r < 4; ++r)
          qw[(g * 4 + r) * 128 + si * 16 + lr] = ea[s5][r];
      }

      // --- Q @ K^T ---
      f32x4 sa[4];
      #pragma unroll
      for (int ni = 0; ni < 4; ++ni) sa[ni] = (f32x4){0.f, 0.f, 0.f, 0.f};
      #pragma unroll
      for (int ni = 0; ni < 4; ++ni)
        #pragma unroll
        for (int kk = 0; kk < 2; ++kk) {
          bf16x8 kf = *(const bf16x8*)&Ks[(ni * 16 + lr) * 64 + kk * 32 + lk];
          sa[ni] = MFMA16(qf[kk], kf, sa[ni]);
        }

      asm volatile("s_waitcnt lgkmcnt(0)" ::: "memory");

      // --- assemble S = (qk + rel)*scale, causal mask, row max ---
      float smax[4] = {-1e30f, -1e30f, -1e30f, -1e30f};
      float sv[4][4];
      #pragma unroll
      for (int ni = 0; ni < 4; ++ni) {
        const int jg = j0 + ni * 16 + lr;
        #pragma unroll
        for (int r = 0; r < 4; ++r) {
          const int di = g * 4 + r;
          const int ig = iw0 + di;
          float s = sa[ni][r] + qw[di * 128 + 63 + (ni * 16 + lr) - (wid * 16 + di)];
          s *= 0.125f;
          s = (jg > ig) ? -1e30f : s;
          sv[ni][r] = s;
          smax[r] = fmaxf(smax[r], s);
        }
      }
      #pragma unroll
      for (int off = 1; off < 16; off <<= 1)
        #pragma unroll
        for (int r = 0; r < 4; ++r)
          smax[r] = fmaxf(smax[r], __shfl_xor(smax[r], off));

      float corr[4];
      #pragma unroll
      for (int r = 0; r < 4; ++r) {
        const float mn = fmaxf(m_r[r], smax[r]);
        corr[r] = __expf(m_r[r] - mn);
        m_r[r] = mn;
      }
      float lb[4] = {0.f, 0.f, 0.f, 0.f};
      #pragma unroll
      for (int ni = 0; ni < 4; ++ni)
        #pragma unroll
        for (int r = 0; r < 4; ++r) {
          const float p = __expf(sv[ni][r] - m_r[r]);
          lb[r] += p;
          pp[(g * 4 + r) * 64 + ni * 16 + lr] = (bf16)p;
        }
      #pragma unroll
      for (int off = 1; off < 16; off <<= 1)
        #pragma unroll
        for (int r = 0; r < 4; ++r)
          lb[r] += __shfl_xor(lb[r], off);
      #pragma unroll
      for (int r = 0; r < 4; ++r) l_r[r] = l_r[r] * corr[r] + lb[r];
      #pragma unroll
      for (int nd = 0; nd < 4; ++nd)
        #pragma unroll
        for (int r = 0; r < 4; ++r)
          oacc[nd][r] *= corr[r];

      asm volatile("s_waitcnt lgkmcnt(0)" ::: "memory");

      // --- P @ V ---
      bf16x8 pf[2];
      pf[0] = *(const bf16x8*)&pp[lr * 64 + lk];
      pf[1] = *(const bf16x8*)&pp[lr * 64 + 32 + lk];
      #pragma unroll
      for (int nd = 0; nd < 4; ++nd)
        #pragma unroll
        for (int kk = 0; kk < 2; ++kk) {
          bf16x8 vf = *(const bf16x8*)&Vs[(nd * 16 + lr) * 64 + kk * 32 + lk];
          oacc[nd] = MFMA16(pf[kk], vf, oacc[nd]);
        }
    }
  }

  // epilogue: AO[b*N+i, h*64+d] = O / l
  const int b = bh >> 4, h = bh & 15;
  #pragma unroll
  for (int nd = 0; nd < 4; ++nd)
    #pragma unroll
    for (int r = 0; r < 4; ++r) {
      const int i = iw0 + g * 4 + r;
      const int d = nd * 16 + lr;
      const float v = oacc[nd][r] / l_r[r];
      AO[((size_t)(b * N + i)) * 1024 + h * 64 + d] = (bf16)v;
    }
}

// ---------------- launch ----------------
extern "C" void kernel_launch(void* const* d_in, const int* in_sizes, int n_in,
                              void* d_out, int out_size, void* d_ws, size_t ws_size,
                              hipStream_t stream) {
  const float* x  = (const float*)d_in[0];
  const float* E  = (const float*)d_in[1];
  // d_in[2] = mask (causal by construction; derived analytically)
  const float* Wq = (const float*)d_in[3];
  const float* Wk = (const float*)d_in[4];
  const float* Wv = (const float*)d_in[5];
  const float* Wo = (const float*)d_in[6];
  const float* bo = (const float*)d_in[7];

  bf16* xb  = (bf16*)d_ws;               // 2048*1024
  bf16* Wqt = xb + 2048 * 1024;          // 1024*1024  (W^T, contiguous q,k,v)
  bf16* Wkt = Wqt + 1024 * 1024;
  bf16* Wvt = Wkt + 1024 * 1024;
  bf16* Wot = Wvt + 1024 * 1024;
  bf16* Eb  = Wot + 1024 * 1024;         // 2048*64 (rows 0..2046 valid)
  bf16* Qh  = Eb + 2048 * 64;            // [B*H, N, 64], contiguous Q,K,Vt
  bf16* Kh  = Qh + 2048 * 1024;
  bf16* Vt  = Kh + 2048 * 1024;
  bf16* AO  = Vt + 2048 * 1024;          // [2048, 1024]
  float* out = (float*)d_out;

  cast_bf16_k<<<dim3(2048), dim3(256), 0, stream>>>(x, xb, 2048 * 1024);
  cast_bf16_k<<<dim3(128), dim3(256), 0, stream>>>(E, Eb, 2047 * 64);
  transpose_cast_k<<<dim3(32, 32), dim3(32, 8), 0, stream>>>(Wq, Wqt, 1024, 1024);
  transpose_cast_k<<<dim3(32, 32), dim3(32, 8), 0, stream>>>(Wk, Wkt, 1024, 1024);
  transpose_cast_k<<<dim3(32, 32), dim3(32, 8), 0, stream>>>(Wv, Wvt, 1024, 1024);
  transpose_cast_k<<<dim3(32, 32), dim3(32, 8), 0, stream>>>(Wo, Wot, 1024, 1024);

  // Q, K, V projections in one launch (z selects weight/output; z==2 writes V^T)
  gemm128<<<dim3(16, 8, 3), dim3(256), 0, stream>>>(xb, Wqt, Qh, nullptr, nullptr, -1);

  attn_kernel<<<dim3(16, 32), dim3(256), 0, stream>>>(Qh, Kh, Vt, Eb, AO);

  // output projection: fp32 + bias
  gemm128<<<dim3(16, 8, 1), dim3(256), 0, stream>>>(AO, Wot, Qh /*unused*/, out, bo, 2);
}

// Round 2
// 132.584 us; speedup vs baseline: 1.0820x; 1.0820x over previous
//
#include <hip/hip_runtime.h>
#include <cstdint>
#include <cstddef>

typedef __bf16 bf16;
typedef __bf16 bf16x8 __attribute__((ext_vector_type(8)));
typedef float  f32x4  __attribute__((ext_vector_type(4)));

#define MFMA16(a,b,c) __builtin_amdgcn_mfma_f32_16x16x32_bf16((a),(b),(c),0,0,0)

__device__ __forceinline__ void gload_lds16(const bf16* g, bf16* l) {
  __builtin_amdgcn_global_load_lds((__attribute__((address_space(1))) void*)(g),
                                   (__attribute__((address_space(3))) void*)(l),
                                   16, 0, 0);
}

// ---------------- cast fp32 -> bf16 (vectorized) ----------------
__global__ void cast_bf16_k(const float* __restrict__ src, bf16* __restrict__ dst, int n) {
  int i = (blockIdx.x * blockDim.x + threadIdx.x) * 4;
  if (i >= n) return;
  float4 v = *(const float4*)(src + i);
  dst[i + 0] = (bf16)v.x;
  dst[i + 1] = (bf16)v.y;
  dst[i + 2] = (bf16)v.z;
  dst[i + 3] = (bf16)v.w;
}

// ---------------- transpose + cast for the 4 weight matrices ----------------
__global__ void transpose4_k(const float* __restrict__ W0, const float* __restrict__ W1,
                             const float* __restrict__ W2, const float* __restrict__ W3,
                             bf16* __restrict__ dst_base) {
  const int z = blockIdx.z;
  const float* src = (z == 0) ? W0 : (z == 1) ? W1 : (z == 2) ? W2 : W3;
  bf16* dst = dst_base + (size_t)z * (1024 * 1024);
  __shared__ float t[32][33];
  const int c0 = blockIdx.x * 32, r0 = blockIdx.y * 32;
  const int x = threadIdx.x, y = threadIdx.y;
  #pragma unroll
  for (int j = 0; j < 32; j += 8) t[y + j][x] = src[(size_t)(r0 + y + j) * 1024 + c0 + x];
  __syncthreads();
  #pragma unroll
  for (int j = 0; j < 32; j += 8)
    dst[(size_t)(c0 + y + j) * 1024 + r0 + x] = (bf16)t[x][y + j];
}

// ---------------- 128x128-tile bf16 GEMM, C = A @ Bt^T ----------------
__global__ __launch_bounds__(256) void gemm128(
    const bf16* __restrict__ A, const bf16* __restrict__ Bt0,
    bf16* __restrict__ O0, float* __restrict__ Of,
    const float* __restrict__ bias, const int mode_sel) {
  constexpr int K = 1024;
  const int z = blockIdx.z;
  const bf16* Bt = Bt0 + (size_t)z * (1024 * 1024);
  bf16* Ob = O0 + (size_t)z * (2048 * 1024);
  const int mode = (mode_sel < 0) ? ((z == 2) ? 1 : 0) : mode_sel;

  const int row0 = blockIdx.x * 128;
  const int col0 = blockIdx.y * 128;

  __shared__ bf16 As[128 * 32];
  __shared__ bf16 Bs[128 * 32];

  const int tid = threadIdx.x;
  const int lane = tid & 63;
  const int wid = tid >> 6;
  const int lr = lane & 15;
  const int lk = (lane >> 4) * 8;
  const int wr = (wid >> 1) * 64;
  const int wc = (wid & 1) * 64;
  const int sr = lane >> 2;
  const int sc = (lane & 3) * 8;

  f32x4 acc[4][4];
  #pragma unroll
  for (int a = 0; a < 4; ++a)
    #pragma unroll
    for (int b = 0; b < 4; ++b) acc[a][b] = (f32x4){0.f, 0.f, 0.f, 0.f};

  for (int k0 = 0; k0 < K; k0 += 32) {
    __syncthreads();
    #pragma unroll
    for (int q = 0; q < 2; ++q) {
      const int chunk = wid * 2 + q;
      const int r = chunk * 16 + sr;
      gload_lds16(A  + (size_t)(row0 + r) * K + k0 + sc, &As[chunk * 512]);
      gload_lds16(Bt + (size_t)(col0 + r) * K + k0 + sc, &Bs[chunk * 512]);
    }
    __syncthreads();
    bf16x8 af[4], bfv[4];
    #pragma unroll
    for (int mi = 0; mi < 4; ++mi) af[mi] = *(const bf16x8*)&As[(wr + mi * 16 + lr) * 32 + lk];
    #pragma unroll
    for (int ni = 0; ni < 4; ++ni) bfv[ni] = *(const bf16x8*)&Bs[(wc + ni * 16 + lr) * 32 + lk];
    #pragma unroll
    for (int mi = 0; mi < 4; ++mi)
      #pragma unroll
      for (int ni = 0; ni < 4; ++ni)
        acc[mi][ni] = MFMA16(af[mi], bfv[ni], acc[mi][ni]);
  }

  #pragma unroll
  for (int mi = 0; mi < 4; ++mi) {
    #pragma unroll
    for (int ni = 0; ni < 4; ++ni) {
      #pragma unroll
      for (int r = 0; r < 4; ++r) {
        const int row = row0 + wr + mi * 16 + (lane >> 4) * 4 + r;
        const int col = col0 + wc + ni * 16 + lr;
        const float v = acc[mi][ni][r];
        if (mode == 2) {
          Of[(size_t)row * 1024 + col] = v + bias[col];
        } else {
          const int b = row >> 10, i = row & 1023;
          const int h = col >> 6, d = col & 63;
          if (mode == 0)
            Ob[(((size_t)(b * 16 + h)) * 1024 + i) * 64 + d] = (bf16)v;
          else
            Ob[(((size_t)(b * 16 + h)) * 64 + d) * 1024 + i] = (bf16)v;
        }
      }
    }
  }
}

// ---------------- causal flash attention with relative-position band ----------------
// Qh,Kh: [B*H, N, 64]; Vt: [B*H, 64, N]; Eb: [2047+,64] bf16. AO: [B*N, 1024] bf16.
// LDS tiles XOR-swizzled: elem (row, col) lives at row*64 + (col ^ ((row&7)<<3)).
__global__ __launch_bounds__(256, 4) void attn_kernel(
    const bf16* __restrict__ Qh, const bf16* __restrict__ Kh,
    const bf16* __restrict__ Vt, const bf16* __restrict__ Eb,
    bf16* __restrict__ AO) {
  constexpr int N = 1024;
  const int bh = blockIdx.x;
  const int yy = blockIdx.y;
  const int qb = (yy < 8) ? yy : 23 - yy;   // pair blocks so each CU's 2 blocks sum to 17 units
  const int i0 = qb * 64;

  const bf16* Qp = Qh + (size_t)bh * N * 64;
  const bf16* Kp = Kh + (size_t)bh * N * 64;
  const bf16* Vp = Vt + (size_t)bh * 64 * N;

  __shared__ bf16 Ks[2][64 * 64];
  __shared__ bf16 Vs[2][64 * 64];
  __shared__ bf16 Ps[4][16 * 64];

  const int tid = threadIdx.x;
  const int lane = tid & 63;
  const int wid = tid >> 6;
  const int lr = lane & 15;
  const int g  = lane >> 4;

  // staging lane map: one gload_lds16 per wave covers 8 rows x 128B, linear LDS dest.
  // LDS byte l*16 -> row srow, swizzled chunk (l&7); source chunk = (l&7)^(srow&7).
  const int srow   = lane >> 3;
  const int schunk = (lane & 7) ^ (srow & 7);

  // Q fragments direct from global (row = lr within wave's 16 rows)
  bf16x8 qf[2];
  {
    const bf16* qrow = Qp + (size_t)(i0 + wid * 16 + lr) * 64 + g * 8;
    qf[0] = *(const bf16x8*)(qrow);
    qf[1] = *(const bf16x8*)(qrow + 32);
  }

  float m_r[4], l_r[4];
  f32x4 oacc[4];
  #pragma unroll
  for (int r = 0; r < 4; ++r) {
    m_r[r] = -3e38f;
    l_r[r] = 0.f;
    oacc[r] = (f32x4){0.f, 0.f, 0.f, 0.f};
  }

  const int nkb = qb + 1;
  const int sib = 3 - wid;          // first E-window fragment needed by this wave
  const int iw0 = i0 + wid * 16;

  // stage K/V block j0 into buffer b (pre-swizzled global source, linear LDS dest)
  #define STAGE_KV(b, j0_)                                                             \
    {                                                                                  \
      const int rb0 = wid * 8, rb1 = 32 + wid * 8;                                     \
      gload_lds16(Kp + (size_t)((j0_) + rb0 + srow) * 64 + schunk * 8, &Ks[b][rb0 * 64]); \
      gload_lds16(Kp + (size_t)((j0_) + rb1 + srow) * 64 + schunk * 8, &Ks[b][rb1 * 64]); \
      gload_lds16(Vp + (size_t)(rb0 + srow) * 1024 + (j0_) + schunk * 8, &Vs[b][rb0 * 64]); \
      gload_lds16(Vp + (size_t)(rb1 + srow) * 1024 + (j0_) + schunk * 8, &Vs[b][rb1 * 64]); \
    }

  STAGE_KV(0, 0);

  for (int kb = 0; kb < nkb; ++kb) {
    const int j0 = kb * 64;
    const int cur = kb & 1;
    __syncthreads();                       // drains vmcnt -> buf[cur] ready, prev reads done
    if (kb + 1 < nkb) STAGE_KV(cur ^ 1, j0 + 64);

    const bf16* kbuf = &Ks[cur][0];
    const bf16* vbuf = &Vs[cur][0];

    // --- Q @ K^T (swizzled LDS reads, conflict-free per quarter-wave) ---
    f32x4 sa[4];
    #pragma unroll
    for (int ni = 0; ni < 4; ++ni) sa[ni] = (f32x4){0.f, 0.f, 0.f, 0.f};
    #pragma unroll
    for (int ni = 0; ni < 4; ++ni)
      #pragma unroll
      for (int kk = 0; kk < 2; ++kk) {
        const int row = ni * 16 + lr;
        bf16x8 kf = *(const bf16x8*)&kbuf[row * 64 + ((kk * 32 + g * 8) ^ ((lr & 7) << 3))];
        sa[ni] = MFMA16(qf[kk], kf, sa[ni]);
      }

    // --- Q @ E-window^T, 5 fragments, B-operand straight from global (L2-hot) ---
    const int rbase = (N - 64) + j0 - i0;
    f32x4 ea[5];
    #pragma unroll
    for (int s5 = 0; s5 < 5; ++s5) ea[s5] = (f32x4){0.f, 0.f, 0.f, 0.f};
    #pragma unroll
    for (int s5 = 0; s5 < 5; ++s5) {
      const int erow = rbase + (sib + s5) * 16 + lr;
      const bf16* ep = Eb + (size_t)erow * 64 + g * 8;
      ea[s5] = MFMA16(qf[0], *(const bf16x8*)(ep), ea[s5]);
      ea[s5] = MFMA16(qf[1], *(const bf16x8*)(ep + 32), ea[s5]);
    }

    // --- skew gather via lane shuffle: rel(ni)[r] at (g,lr) = ea[ni + (lr>di)][r]
    //     from srclane g*16 + ((lr-di-1)&15), di = g*4+r ---
    float smax[4] = {-3e38f, -3e38f, -3e38f, -3e38f};
    #pragma unroll
    for (int r = 0; r < 4; ++r) {
      const int di = g * 4 + r;
      const int sl = (g << 4) | ((lr - di - 1) & 15);
      const float sh0 = __shfl(ea[0][r], sl);
      const float sh1 = __shfl(ea[1][r], sl);
      const float sh2 = __shfl(ea[2][r], sl);
      const float sh3 = __shfl(ea[3][r], sl);
      const float sh4 = __shfl(ea[4][r], sl);
      const bool hi = (lr > di);
      const float rel[4] = {hi ? sh1 : sh0, hi ? sh2 : sh1, hi ? sh3 : sh2, hi ? sh4 : sh3};
      const int ig = iw0 + di;
      #pragma unroll
      for (int ni = 0; ni < 4; ++ni) {
        float s = (sa[ni][r] + rel[ni]) * 0.125f;
        s = (j0 + ni * 16 + lr > ig) ? -1e30f : s;
        sa[ni][r] = s;
        smax[r] = fmaxf(smax[r], s);
      }
    }
    #pragma unroll
    for (int off = 1; off < 16; off <<= 1)
      #pragma unroll
      for (int r = 0; r < 4; ++r)
        smax[r] = fmaxf(smax[r], __shfl_xor(smax[r], off));

    float corr[4], lb[4] = {0.f, 0.f, 0.f, 0.f};
    #pragma unroll
    for (int r = 0; r < 4; ++r) {
      const float mn = fmaxf(m_r[r], smax[r]);
      corr[r] = __expf(m_r[r] - mn);
      m_r[r] = mn;
    }
    #pragma unroll
    for (int r = 0; r < 4; ++r) {
      const int di = g * 4 + r;
      #pragma unroll
      for (int ni = 0; ni < 4; ++ni) {
        const float p = __expf(sa[ni][r] - m_r[r]);
        lb[r] += p;
        Ps[wid][di * 64 + ((ni * 16 + lr) ^ ((di & 7) << 3))] = (bf16)p;
      }
    }
    #pragma unroll
    for (int off = 1; off < 16; off <<= 1)
      #pragma unroll
      for (int r = 0; r < 4; ++r)
        lb[r] += __shfl_xor(lb[r], off);
    #pragma unroll
    for (int r = 0; r < 4; ++r) l_r[r] = l_r[r] * corr[r] + lb[r];
    #pragma unroll
    for (int nd = 0; nd < 4; ++nd)
      #pragma unroll
      for (int r = 0; r < 4; ++r)
        oacc[nd][r] *= corr[r];

    // --- P @ V (per-wave private Ps; compiler orders same-array LDS accesses) ---
    bf16x8 pf[2];
    pf[0] = *(const bf16x8*)&Ps[wid][lr * 64 + ((g * 8) ^ ((lr & 7) << 3))];
    pf[1] = *(const bf16x8*)&Ps[wid][lr * 64 + ((32 + g * 8) ^ ((lr & 7) << 3))];
    #pragma unroll
    for (int nd = 0; nd < 4; ++nd)
      #pragma unroll
      for (int kk = 0; kk < 2; ++kk) {
        const int row = nd * 16 + lr;
        bf16x8 vf = *(const bf16x8*)&vbuf[row * 64 + ((kk * 32 + g * 8) ^ ((lr & 7) << 3))];
        oacc[nd] = MFMA16(pf[kk], vf, oacc[nd]);
      }
  }

  // epilogue: AO[b*N+i, h*64+d] = O / l
  const int b = bh >> 4, h = bh & 15;
  #pragma unroll
  for (int nd = 0; nd < 4; ++nd)
    #pragma unroll
    for (int r = 0; r < 4; ++r) {
      const int i = iw0 + g * 4 + r;
      const int d = nd * 16 + lr;
      const float v = oacc[nd][r] / l_r[r];
      AO[((size_t)(b * N + i)) * 1024 + h * 64 + d] = (bf16)v;
    }
}

// ---------------- launch ----------------
extern "C" void kernel_launch(void* const* d_in, const int* in_sizes, int n_in,
                              void* d_out, int out_size, void* d_ws, size_t ws_size,
                              hipStream_t stream) {
  const float* x  = (const float*)d_in[0];
  const float* E  = (const float*)d_in[1];
  // d_in[2] = mask (causal by construction; derived analytically)
  const float* Wq = (const float*)d_in[3];
  const float* Wk = (const float*)d_in[4];
  const float* Wv = (const float*)d_in[5];
  const float* Wo = (const float*)d_in[6];
  const float* bo = (const float*)d_in[7];

  bf16* xb  = (bf16*)d_ws;               // 2048*1024
  bf16* Wqt = xb + 2048 * 1024;          // 4 x 1024*1024 (Wq,Wk,Wv,Wo transposed)
  bf16* Wot = Wqt + 3 * 1024 * 1024;
  bf16* Eb  = Wqt + 4 * 1024 * 1024;     // 2048*64 (rows 0..2046 valid)
  bf16* Qh  = Eb + 2048 * 64;            // [B*H, N, 64], contiguous Q,K,Vt
  bf16* Vt  = Qh + 2 * 2048 * 1024;
  bf16* AO  = Qh + 3 * 2048 * 1024;      // [2048, 1024]
  float* out = (float*)d_out;

  cast_bf16_k<<<dim3(2048), dim3(256), 0, stream>>>(x, xb, 2048 * 1024);
  cast_bf16_k<<<dim3(128), dim3(256), 0, stream>>>(E, Eb, 2047 * 64);
  transpose4_k<<<dim3(32, 32, 4), dim3(32, 8), 0, stream>>>(Wq, Wk, Wv, Wo, Wqt);

  // Q, K, V projections in one launch (z selects weight/output; z==2 writes V^T)
  gemm128<<<dim3(16, 8, 3), dim3(256), 0, stream>>>(xb, Wqt, Qh, nullptr, nullptr, -1);

  attn_kernel<<<dim3(32, 16), dim3(256), 0, stream>>>(Qh, Qh + 2048 * 1024, Vt, Eb, AO);

  // output projection: fp32 + bias
  gemm128<<<dim3(16, 8, 1), dim3(256), 0, stream>>>(AO, Wot, nullptr, out, bo, 2);
}

// Round 3
// 109.170 us; speedup vs baseline: 1.3140x; 1.2145x over previous
//
#include <hip/hip_runtime.h>
#include <cstdint>
#include <cstddef>

typedef __bf16 bf16;
typedef __bf16 bf16x8 __attribute__((ext_vector_type(8)));
typedef float  f32x4  __attribute__((ext_vector_type(4)));

#define MFMA16(a,b,c) __builtin_amdgcn_mfma_f32_16x16x32_bf16((a),(b),(c),0,0,0)

__device__ __forceinline__ void gload_lds16(const bf16* g, bf16* l) {
  __builtin_amdgcn_global_load_lds((__attribute__((address_space(1))) void*)(g),
                                   (__attribute__((address_space(3))) void*)(l),
                                   16, 0, 0);
}

// ---------------- cast fp32 -> bf16 (vectorized) ----------------
__global__ void cast_bf16_k(const float* __restrict__ src, bf16* __restrict__ dst, int n) {
  int i = (blockIdx.x * blockDim.x + threadIdx.x) * 4;
  if (i >= n) return;
  float4 v = *(const float4*)(src + i);
  dst[i + 0] = (bf16)v.x;
  dst[i + 1] = (bf16)v.y;
  dst[i + 2] = (bf16)v.z;
  dst[i + 3] = (bf16)v.w;
}

// ---------------- transpose + cast for the 4 weight matrices ----------------
__global__ void transpose4_k(const float* __restrict__ W0, const float* __restrict__ W1,
                             const float* __restrict__ W2, const float* __restrict__ W3,
                             bf16* __restrict__ dst_base) {
  const int z = blockIdx.z;
  const float* src = (z == 0) ? W0 : (z == 1) ? W1 : (z == 2) ? W2 : W3;
  bf16* dst = dst_base + (size_t)z * (1024 * 1024);
  __shared__ float t[32][33];
  const int c0 = blockIdx.x * 32, r0 = blockIdx.y * 32;
  const int x = threadIdx.x, y = threadIdx.y;
  #pragma unroll
  for (int j = 0; j < 32; j += 8) t[y + j][x] = src[(size_t)(r0 + y + j) * 1024 + c0 + x];
  __syncthreads();
  #pragma unroll
  for (int j = 0; j < 32; j += 8)
    dst[(size_t)(c0 + y + j) * 1024 + r0 + x] = (bf16)t[x][y + j];
}

// ---------------- 64x128-tile bf16 GEMM, double-buffered 2-phase ----------------
// A: [M,1024] bf16; Bt: [Ncols,1024] bf16 (=B^T). mode 0: QKV epilogue (col>>10
// selects Q/K/V region; V written transposed). mode 2: fp32 out + bias.
__global__ __launch_bounds__(256) void gemm64(
    const bf16* __restrict__ A, const bf16* __restrict__ Bt,
    bf16* __restrict__ QKV, float* __restrict__ Of,
    const float* __restrict__ bias, const int mode) {
  constexpr int K = 1024;
  const int row0 = blockIdx.x * 64;
  const int col0 = blockIdx.y * 128;

  __shared__ bf16 As[2][64 * 32];
  __shared__ bf16 Bs[2][128 * 32];

  const int tid = threadIdx.x;
  const int lane = tid & 63;
  const int wid = tid >> 6;
  const int lr = lane & 15;
  const int lk = (lane >> 4) * 8;
  const int sr = lane >> 2;
  const int sc = (lane & 3) * 8;

  f32x4 acc[4][2];
  #pragma unroll
  for (int a = 0; a < 4; ++a)
    #pragma unroll
    for (int b = 0; b < 2; ++b) acc[a][b] = (f32x4){0.f, 0.f, 0.f, 0.f};

  #define STG(bb, k0_)                                                                  \
    {                                                                                   \
      gload_lds16(A  + (size_t)(row0 + wid * 16 + sr) * K + (k0_) + sc, &As[bb][wid * 512]); \
      gload_lds16(Bt + (size_t)(col0 + wid * 32 + sr) * K + (k0_) + sc, &Bs[bb][wid * 1024]); \
      gload_lds16(Bt + (size_t)(col0 + wid * 32 + 16 + sr) * K + (k0_) + sc, &Bs[bb][wid * 1024 + 512]); \
    }

  STG(0, 0);
  for (int t = 0; t < K / 32; ++t) {
    __syncthreads();                      // drains vmcnt -> buf[t&1] staged
    if (t + 1 < K / 32) STG((t + 1) & 1, (t + 1) * 32);
    const bf16* as = &As[t & 1][0];
    const bf16* bs = &Bs[t & 1][0];
    bf16x8 af[4], bfv[2];
    #pragma unroll
    for (int mi = 0; mi < 4; ++mi) af[mi] = *(const bf16x8*)&as[(mi * 16 + lr) * 32 + lk];
    #pragma unroll
    for (int ni = 0; ni < 2; ++ni) bfv[ni] = *(const bf16x8*)&bs[(wid * 32 + ni * 16 + lr) * 32 + lk];
    #pragma unroll
    for (int mi = 0; mi < 4; ++mi)
      #pragma unroll
      for (int ni = 0; ni < 2; ++ni)
        acc[mi][ni] = MFMA16(af[mi], bfv[ni], acc[mi][ni]);
  }
  #undef STG

  #pragma unroll
  for (int mi = 0; mi < 4; ++mi) {
    #pragma unroll
    for (int ni = 0; ni < 2; ++ni) {
      #pragma unroll
      for (int r = 0; r < 4; ++r) {
        const int row = row0 + mi * 16 + (lane >> 4) * 4 + r;
        const int col = col0 + wid * 32 + ni * 16 + lr;
        const float v = acc[mi][ni][r];
        if (mode == 2) {
          Of[(size_t)row * 1024 + col] = v + bias[col];
        } else {
          const int b = row >> 10, i = row & 1023;
          const int which = col >> 10, cc = col & 1023;
          const int h = cc >> 6, d = cc & 63;
          if (which < 2)
            QKV[(size_t)which * 2097152 + (((size_t)(b * 16 + h)) * 1024 + i) * 64 + d] = (bf16)v;
          else
            QKV[(size_t)2 * 2097152 + (((size_t)(b * 16 + h)) * 64 + d) * 1024 + i] = (bf16)v;
        }
      }
    }
  }
}

// ---------------- causal flash attention, split-K partials ----------------
// 24 tasks per bh: qb<8 whole; qb>=8 split into kb [0,7] and [8,qb].
// Writes unnormalized O (fp32) + m,l per row to workspace; merge_k combines.
__device__ const int task_order[24] = {7, 8, 10, 12, 14, 16, 18, 20, 22, 23,
                                       6, 21, 5, 19, 4, 17, 3, 15, 2, 13, 1, 11, 0, 9};

__global__ __launch_bounds__(256, 4) void attn_kernel(
    const bf16* __restrict__ Qh, const bf16* __restrict__ Kh,
    const bf16* __restrict__ Vt, const bf16* __restrict__ Eb,
    float* __restrict__ OP, float* __restrict__ MP, float* __restrict__ LP) {
  constexpr int N = 1024;
  const int bh = blockIdx.x;
  const int t = task_order[blockIdx.y];
  int qb, kb0, kb1, s;
  if (t < 8) { qb = t; kb0 = 0; kb1 = t; s = 0; }
  else {
    const int u = t - 8;
    qb = 8 + (u >> 1);
    s = u & 1;
    if (s == 0) { kb0 = 0; kb1 = 7; } else { kb0 = 8; kb1 = qb; }
  }
  const int i0 = qb * 64;

  const bf16* Qp = Qh + (size_t)bh * N * 64;
  const bf16* Kp = Kh + (size_t)bh * N * 64;
  const bf16* Vp = Vt + (size_t)bh * 64 * N;

  __shared__ bf16 Ks[2][64 * 64];
  __shared__ bf16 Vs[2][64 * 64];
  __shared__ bf16 Ps[4][16 * 64];

  const int tid = threadIdx.x;
  const int lane = tid & 63;
  const int wid = tid >> 6;
  const int lr = lane & 15;
  const int g  = lane >> 4;

  const int srow   = lane >> 3;
  const int schunk = (lane & 7) ^ (srow & 7);

  bf16x8 qf[2];
  {
    const bf16* qrow = Qp + (size_t)(i0 + wid * 16 + lr) * 64 + g * 8;
    qf[0] = *(const bf16x8*)(qrow);
    qf[1] = *(const bf16x8*)(qrow + 32);
  }

  float m_r[4], l_r[4];
  f32x4 oacc[4];
  #pragma unroll
  for (int r = 0; r < 4; ++r) {
    m_r[r] = -3e38f;
    l_r[r] = 0.f;
    oacc[r] = (f32x4){0.f, 0.f, 0.f, 0.f};
  }

  const int sib = 3 - wid;
  const int iw0 = i0 + wid * 16;

  #define STAGE_KV(b, j0_)                                                             \
    {                                                                                  \
      const int rb0 = wid * 8, rb1 = 32 + wid * 8;                                     \
      gload_lds16(Kp + (size_t)((j0_) + rb0 + srow) * 64 + schunk * 8, &Ks[b][rb0 * 64]); \
      gload_lds16(Kp + (size_t)((j0_) + rb1 + srow) * 64 + schunk * 8, &Ks[b][rb1 * 64]); \
      gload_lds16(Vp + (size_t)(rb0 + srow) * 1024 + (j0_) + schunk * 8, &Vs[b][rb0 * 64]); \
      gload_lds16(Vp + (size_t)(rb1 + srow) * 1024 + (j0_) + schunk * 8, &Vs[b][rb1 * 64]); \
    }

  STAGE_KV(0, kb0 * 64);

  for (int kb = kb0; kb <= kb1; ++kb) {
    const int j0 = kb * 64;
    const int cur = (kb - kb0) & 1;
    __syncthreads();
    if (kb < kb1) STAGE_KV(cur ^ 1, j0 + 64);

    const bf16* kbuf = &Ks[cur][0];
    const bf16* vbuf = &Vs[cur][0];

    // issue E-fragment loads early (L2-hot); consumed after QK^T
    const int rbase = (N - 64) + j0 - i0;
    bf16x8 eA[5], eB[5];
    #pragma unroll
    for (int s5 = 0; s5 < 5; ++s5) {
      const bf16* ep = Eb + (size_t)(rbase + (sib + s5) * 16 + lr) * 64 + g * 8;
      eA[s5] = *(const bf16x8*)(ep);
      eB[s5] = *(const bf16x8*)(ep + 32);
    }

    // --- Q @ K^T (swizzled LDS reads) ---
    f32x4 sa[4];
    #pragma unroll
    for (int ni = 0; ni < 4; ++ni) sa[ni] = (f32x4){0.f, 0.f, 0.f, 0.f};
    #pragma unroll
    for (int ni = 0; ni < 4; ++ni)
      #pragma unroll
      for (int kk = 0; kk < 2; ++kk) {
        const int row = ni * 16 + lr;
        bf16x8 kf = *(const bf16x8*)&kbuf[row * 64 + ((kk * 32 + g * 8) ^ ((lr & 7) << 3))];
        sa[ni] = MFMA16(qf[kk], kf, sa[ni]);
      }

    // --- Q @ E-window^T, 5 fragments ---
    f32x4 ea[5];
    #pragma unroll
    for (int s5 = 0; s5 < 5; ++s5) {
      ea[s5] = (f32x4){0.f, 0.f, 0.f, 0.f};
      ea[s5] = MFMA16(qf[0], eA[s5], ea[s5]);
      ea[s5] = MFMA16(qf[1], eB[s5], ea[s5]);
    }

    // --- skew gather via lane shuffle ---
    float smax[4] = {-3e38f, -3e38f, -3e38f, -3e38f};
    #pragma unroll
    for (int r = 0; r < 4; ++r) {
      const int di = g * 4 + r;
      const int sl = (g << 4) | ((lr - di - 1) & 15);
      const float sh0 = __shfl(ea[0][r], sl);
      const float sh1 = __shfl(ea[1][r], sl);
      const float sh2 = __shfl(ea[2][r], sl);
      const float sh3 = __shfl(ea[3][r], sl);
      const float sh4 = __shfl(ea[4][r], sl);
      const bool hi = (lr > di);
      const float rel[4] = {hi ? sh1 : sh0, hi ? sh2 : sh1, hi ? sh3 : sh2, hi ? sh4 : sh3};
      const int ig = iw0 + di;
      #pragma unroll
      for (int ni = 0; ni < 4; ++ni) {
        float sv = (sa[ni][r] + rel[ni]) * 0.125f;
        sv = (j0 + ni * 16 + lr > ig) ? -1e30f : sv;
        sa[ni][r] = sv;
        smax[r] = fmaxf(smax[r], sv);
      }
    }
    #pragma unroll
    for (int off = 1; off < 16; off <<= 1)
      #pragma unroll
      for (int r = 0; r < 4; ++r)
        smax[r] = fmaxf(smax[r], __shfl_xor(smax[r], off));

    float corr[4], lb[4] = {0.f, 0.f, 0.f, 0.f};
    #pragma unroll
    for (int r = 0; r < 4; ++r) {
      const float mn = fmaxf(m_r[r], smax[r]);
      corr[r] = __expf(m_r[r] - mn);
      m_r[r] = mn;
    }
    #pragma unroll
    for (int r = 0; r < 4; ++r) {
      const int di = g * 4 + r;
      #pragma unroll
      for (int ni = 0; ni < 4; ++ni) {
        const float p = __expf(sa[ni][r] - m_r[r]);
        lb[r] += p;
        Ps[wid][di * 64 + ((ni * 16 + lr) ^ ((di & 7) << 3))] = (bf16)p;
      }
    }
    #pragma unroll
    for (int off = 1; off < 16; off <<= 1)
      #pragma unroll
      for (int r = 0; r < 4; ++r)
        lb[r] += __shfl_xor(lb[r], off);
    #pragma unroll
    for (int r = 0; r < 4; ++r) l_r[r] = l_r[r] * corr[r] + lb[r];
    #pragma unroll
    for (int nd = 0; nd < 4; ++nd)
      #pragma unroll
      for (int r = 0; r < 4; ++r)
        oacc[nd][r] *= corr[r];

    // --- P @ V ---
    bf16x8 pf[2];
    pf[0] = *(const bf16x8*)&Ps[wid][lr * 64 + ((g * 8) ^ ((lr & 7) << 3))];
    pf[1] = *(const bf16x8*)&Ps[wid][lr * 64 + ((32 + g * 8) ^ ((lr & 7) << 3))];
    #pragma unroll
    for (int nd = 0; nd < 4; ++nd)
      #pragma unroll
      for (int kk = 0; kk < 2; ++kk) {
        const int row = nd * 16 + lr;
        bf16x8 vf = *(const bf16x8*)&vbuf[row * 64 + ((kk * 32 + g * 8) ^ ((lr & 7) << 3))];
        oacc[nd] = MFMA16(pf[kk], vf, oacc[nd]);
      }
  }
  #undef STAGE_KV

  // partial epilogue: unnormalized O + m,l
  const int p = (bh * 16 + qb) * 2 + s;
  float* Op = OP + (size_t)p * 4096;
  #pragma unroll
  for (int nd = 0; nd < 4; ++nd)
    #pragma unroll
    for (int r = 0; r < 4; ++r)
      Op[(size_t)(wid * 16 + g * 4 + r) * 64 + nd * 16 + lr] = oacc[nd][r];
  if (lr == 0) {
    #pragma unroll
    for (int r = 0; r < 4; ++r) {
      MP[p * 64 + wid * 16 + g * 4 + r] = m_r[r];
      LP[p * 64 + wid * 16 + g * 4 + r] = l_r[r];
    }
  }
}

// ---------------- merge split-K partials -> AO bf16 ----------------
__global__ __launch_bounds__(256) void merge_k(const float* __restrict__ OP,
                                               const float* __restrict__ MP,
                                               const float* __restrict__ LP,
                                               bf16* __restrict__ AO) {
  const int bh = blockIdx.x;     // 32
  const int qb = blockIdx.y;     // 16
  const int tid = threadIdx.x;
  const int row = tid >> 2;
  const int c0 = (tid & 3) * 16;
  const int p0 = (bh * 16 + qb) * 2;

  const float* O0 = OP + (size_t)p0 * 4096 + row * 64 + c0;
  float o[16];
  #pragma unroll
  for (int j = 0; j < 16; j += 4) *(f32x4*)&o[j] = *(const f32x4*)&O0[j];

  if (qb >= 8) {
    const float* O1 = OP + (size_t)(p0 + 1) * 4096 + row * 64 + c0;
    const float m0 = MP[p0 * 64 + row], l0 = LP[p0 * 64 + row];
    const float m1 = MP[(p0 + 1) * 64 + row], l1 = LP[(p0 + 1) * 64 + row];
    const float m = fmaxf(m0, m1);
    const float a0 = __expf(m0 - m), a1 = __expf(m1 - m);
    const float inv = 1.f / (l0 * a0 + l1 * a1);
    #pragma unroll
    for (int j = 0; j < 16; ++j) o[j] = (o[j] * a0 + O1[j] * a1) * inv;
  } else {
    const float inv = 1.f / LP[p0 * 64 + row];
    #pragma unroll
    for (int j = 0; j < 16; ++j) o[j] *= inv;
  }

  const int b = bh >> 4, h = bh & 15;
  bf16* dst = AO + ((size_t)(b * 1024) + qb * 64 + row) * 1024 + h * 64 + c0;
  #pragma unroll
  for (int j = 0; j < 16; ++j) dst[j] = (bf16)o[j];
}

// ---------------- launch ----------------
extern "C" void kernel_launch(void* const* d_in, const int* in_sizes, int n_in,
                              void* d_out, int out_size, void* d_ws, size_t ws_size,
                              hipStream_t stream) {
  const float* x  = (const float*)d_in[0];
  const float* E  = (const float*)d_in[1];
  // d_in[2] = mask (causal by construction)
  const float* Wq = (const float*)d_in[3];
  const float* Wk = (const float*)d_in[4];
  const float* Wv = (const float*)d_in[5];
  const float* Wo = (const float*)d_in[6];
  const float* bo = (const float*)d_in[7];

  bf16* xb  = (bf16*)d_ws;               // 2M
  bf16* Wqt = xb + 2048 * 1024;          // 4M (Wq,Wk,Wv,Wo transposed, contiguous)
  bf16* Wot = Wqt + 3 * 1024 * 1024;
  bf16* Eb  = Wqt + 4 * 1024 * 1024;     // 128K
  bf16* Qh  = Eb + 2048 * 64;            // 3 x 2M (Q, K, V^T)
  bf16* AO  = Qh + 3 * 2048 * 1024;      // 2M
  float* OP = (float*)(AO + 2048 * 1024); // 1024 slots x 4096 f32 = 16MB
  float* MPp = OP + (size_t)1024 * 4096;  // 64K f32
  float* LPp = MPp + 1024 * 64;
  float* out = (float*)d_out;

  cast_bf16_k<<<dim3(2048), dim3(256), 0, stream>>>(x, xb, 2048 * 1024);
  cast_bf16_k<<<dim3(128), dim3(256), 0, stream>>>(E, Eb, 2047 * 64);
  transpose4_k<<<dim3(32, 32, 4), dim3(32, 8), 0, stream>>>(Wq, Wk, Wv, Wo, Wqt);

  // fused QKV projection: [2048,1024] @ [3072,1024]^T
  gemm64<<<dim3(32, 24), dim3(256), 0, stream>>>(xb, Wqt, Qh, nullptr, nullptr, 0);

  attn_kernel<<<dim3(32, 24), dim3(256), 0, stream>>>(
      Qh, Qh + 2048 * 1024, Qh + 2 * 2048 * 1024, Eb, OP, MPp, LPp);

  merge_k<<<dim3(32, 16), dim3(256), 0, stream>>>(OP, MPp, LPp, AO);

  // output projection: fp32 + bias
  gemm64<<<dim3(32, 8), dim3(256), 0, stream>>>(AO, Wot, nullptr, out, bo, 2);
}